// Round 4
// baseline (304.758 us; speedup 1.0000x reference)
//
#include <hip/hip_runtime.h>
#include <hip/hip_bf16.h>

#define OUT_CH 4096
#define IN_FEAT 11008
#define NVEC (IN_FEAT / 4)          // 2752 vec4 per row
#define PAIRVEC (2 * NVEC)          // 5504 vec4 per row-pair
#define NB 21                       // full 256-vec4 batches per pair (21*256 = 5376)
#define TAILN (PAIRVEC - NB * 256)  // 128 tail lanes
#define DEPTH 7                     // software-pipeline depth (21 = 3*7)
#define EPS 1e-5f
#define BIT_BOUND 6.0f

// Native clang vector type — accepted by __builtin_nontemporal_{load,store}.
typedef float fvec4 __attribute__((ext_vector_type(4)));

// v5: persistent software-pipelined streaming.
//   Ledger so far: store policy (v3: null), load/store schedule (v4: null),
//   load policy (v2/v4 diff: nt loads required, cached loads +16us).
//   Remaining untested axis: per-wave burst structure. v1/v4 waves issue
//   ~11 loads ONCE, drain, compute a long dependent IEEE-div chain, store,
//   exit — outstanding-read depth oscillates. Copy benches that hit
//   6.29 TB/s sustain depth with a pipelined loop.
// Structure: 2048 blocks x 256 threads = exactly 8 blocks/CU, all 32
// waves/CU resident (VGPR ~50 < 64, no LDS). Block owns rows {2b, 2b+1}
// = 5504 vec4 = 21 batches + 128 tail. Depth-7 circular register buffer:
// every wave keeps 7 loads in flight from prologue to epilogue.
// Batch 10 straddles the row boundary -> per-lane s/qmax via cndmask
// (identical per-element arithmetic; absmax unaffected).
// nt loads + nt stores (proven best). Exact IEEE div + rintf (half-even).
__global__ __launch_bounds__(256) void fake_quant_kernel(
    const float* __restrict__ weight,
    const float* __restrict__ alh,
    const float* __restrict__ bit,
    float* __restrict__ out)
{
    const int pair = blockIdx.x;        // 0..2047
    const int r0 = 2 * pair;
    const int tid = threadIdx.x;

    const fvec4* __restrict__ wrow =
        (const fvec4*)(weight + (size_t)r0 * IN_FEAT);
    fvec4* __restrict__ orow = (fvec4*)(out + (size_t)r0 * IN_FEAT);

    // Prologue: fill the pipeline — 7 loads in flight per thread.
    fvec4 w[DEPTH];
    #pragma unroll
    for (int j = 0; j < DEPTH; ++j)
        w[j] = __builtin_nontemporal_load(&wrow[tid + j * 256]);

    // Per-row quant params for both rows (wave-uniform scalar loads;
    // overlap with the vector loads above).
    const float s0 = fmaxf(alh[r0], EPS);
    const float s1 = fmaxf(alh[r0 + 1], EPS);
    const float be0 = fminf(fmaxf(fabsf(bit[r0]), 1.0f), BIT_BOUND);
    const float be1 = fminf(fmaxf(fabsf(bit[r0 + 1]), 1.0f), BIT_BOUND);
    const float qm0 = fmaxf(exp2f(rintf(be0) - 1.0f) - 1.0f, 1.0f);
    const float qm1 = fmaxf(exp2f(rintf(be1) - 1.0f) - 1.0f, 1.0f);

    // Exact IEEE division (matches np w/scale bit-exactly; rintf = half-even).
    auto q4 = [](fvec4 v, float s, float qmax) -> fvec4 {
        const float qmin = -qmax;
        fvec4 r;
        r.x = fminf(fmaxf(rintf(v.x / s), qmin), qmax) * s;
        r.y = fminf(fmaxf(rintf(v.y / s), qmin), qmax) * s;
        r.z = fminf(fmaxf(rintf(v.z / s), qmin), qmax) * s;
        r.w = fminf(fmaxf(rintf(v.w / s), qmin), qmax) * s;
        return r;
    };

    // Steady state: k = 0..13 — consume batch k, issue load for batch k+7.
    // unroll 7 (14 = 2*7) keeps k%DEPTH a compile-time constant.
    #pragma unroll 7
    for (int k = 0; k < NB - DEPTH; ++k) {
        const int vidx = tid + k * 256;
        const bool in_r1 = vidx >= NVEC;
        const float s = in_r1 ? s1 : s0;
        const float qm = in_r1 ? qm1 : qm0;
        __builtin_nontemporal_store(q4(w[k % DEPTH], s, qm), &orow[vidx]);
        w[k % DEPTH] = __builtin_nontemporal_load(&wrow[vidx + DEPTH * 256]);
    }
    // Epilogue: k = 14..20 — drain the pipeline.
    #pragma unroll
    for (int k = NB - DEPTH; k < NB; ++k) {
        const int vidx = tid + k * 256;
        const bool in_r1 = vidx >= NVEC;
        const float s = in_r1 ? s1 : s0;
        const float qm = in_r1 ? qm1 : qm0;
        __builtin_nontemporal_store(q4(w[k % DEPTH], s, qm), &orow[vidx]);
    }
    // Tail: 128 lanes, vidx 5376..5503, all row1.
    if (tid < TAILN) {
        const int vidx = NB * 256 + tid;
        fvec4 v = __builtin_nontemporal_load(&wrow[vidx]);
        __builtin_nontemporal_store(q4(v, s1, qm1), &orow[vidx]);
    }
}

extern "C" void kernel_launch(void* const* d_in, const int* in_sizes, int n_in,
                              void* d_out, int out_size, void* d_ws, size_t ws_size,
                              hipStream_t stream) {
    const float* weight = (const float*)d_in[0];
    const float* alh    = (const float*)d_in[1];
    const float* bit    = (const float*)d_in[2];
    // d_in[3] = init_weight_bit (unused in forward at init)
    float* out = (float*)d_out;

    fake_quant_kernel<<<OUT_CH / 2, 256, 0, stream>>>(weight, alh, bit, out);
}

// Round 5
// 294.461 us; speedup vs baseline: 1.0350x; 1.0350x over previous
//
#include <hip/hip_runtime.h>
#include <hip/hip_bf16.h>

#define OUT_CH 4096
#define IN_FEAT 11008
#define NVEC (IN_FEAT / 4)   // 2752 float4 per row
#define EPS 1e-5f
#define BIT_BOUND 6.0f

// Native clang vector type — accepted by __builtin_nontemporal_{load,store}
// (HIP's float4 is a struct and is rejected).
typedef float fvec4 __attribute__((ext_vector_type(4)));

// FINAL (v6 = revert to v4, session best ~295.6 us; v1 variant 294.2-297.1).
//
// Session ledger (dur_us = 2 harness re-poison fills ~220us + kernel):
//   v1 nt/nt phased 8+2+tail          : kernel ~76 us
//   v2 cached loads (+confounds)      : ~94 us  -> nt LOADS are load-bearing
//   v3 cached stores                  : ~81 us  -> cached stores no better
//   v4 nt/nt, ALL loads upfront       : ~72 us  <- BEST
//   v5 depth-7 pipelined, persistent  : ~86 us  -> interleaved nt stores put
//                                                 store-retirement on the
//                                                 load-consume vmcnt path
// Surviving model: nt stores retire slowly; the optimal schedule never
// waits on them: issue ALL loads, compute, issue ALL stores, exit. Single
// wait point, no mid-stream store drain.
// Roofline: 361 MB irreducible traffic; v4 streams at ~5.0 TB/s vs the
// 6.29 TB/s copy reference; the residual ~15 us survived 5 orthogonal
// structural experiments (store policy / load policy / schedule /
// pipelining / persistence) — practical floor for this op in this harness.
__global__ __launch_bounds__(256) void fake_quant_kernel(
    const float* __restrict__ weight,
    const float* __restrict__ alh,
    const float* __restrict__ bit,
    float* __restrict__ out)
{
    const int row = blockIdx.x;
    const int tid = threadIdx.x;

    const fvec4* __restrict__ wrow =
        (const fvec4*)(weight + (size_t)row * IN_FEAT);
    fvec4* __restrict__ orow = (fvec4*)(out + (size_t)row * IN_FEAT);

    // Issue all 10 full-batch loads first: covers vec4 indices 0..2559.
    fvec4 w[10];
    #pragma unroll
    for (int j = 0; j < 10; ++j)
        w[j] = __builtin_nontemporal_load(&wrow[tid + j * 256]);

    // Per-row quant params (forward values; STE affects only gradients).
    // Wave-uniform scalar loads; overlap with the vector loads above.
    const float s = fmaxf(alh[row], EPS);
    const float b_eff = fminf(fmaxf(fabsf(bit[row]), 1.0f), BIT_BOUND);
    const float b_r = rintf(b_eff);                        // jnp.round = half-to-even
    const float qmax = fmaxf(exp2f(b_r - 1.0f) - 1.0f, 1.0f);
    const float qmin = -qmax;

    // Exact IEEE division (matches np w/scale bit-exactly; rintf = half-even).
    auto q4 = [&](fvec4 v) -> fvec4 {
        fvec4 r;
        r.x = fminf(fmaxf(rintf(v.x / s), qmin), qmax) * s;
        r.y = fminf(fmaxf(rintf(v.y / s), qmin), qmax) * s;
        r.z = fminf(fmaxf(rintf(v.z / s), qmin), qmax) * s;
        r.w = fminf(fmaxf(rintf(v.w / s), qmin), qmax) * s;
        return r;
    };

    #pragma unroll
    for (int j = 0; j < 10; ++j)
        __builtin_nontemporal_store(q4(w[j]), &orow[tid + j * 256]);

    // Remainder: 2752 - 2560 = 192 lanes, one vec4 each.
    if (tid < (NVEC - 2560)) {
        fvec4 wt = __builtin_nontemporal_load(&wrow[tid + 2560]);
        __builtin_nontemporal_store(q4(wt), &orow[tid + 2560]);
    }
}

extern "C" void kernel_launch(void* const* d_in, const int* in_sizes, int n_in,
                              void* d_out, int out_size, void* d_ws, size_t ws_size,
                              hipStream_t stream) {
    const float* weight = (const float*)d_in[0];
    const float* alh    = (const float*)d_in[1];
    const float* bit    = (const float*)d_in[2];
    // d_in[3] = init_weight_bit (unused in forward at init)
    float* out = (float*)d_out;

    fake_quant_kernel<<<OUT_CH, 256, 0, stream>>>(weight, alh, bit, out);
}